// Round 4
// baseline (978.144 us; speedup 1.0000x reference)
//
#include <hip/hip_runtime.h>
#include <hip/hip_bf16.h>

// Problem constants (from reference)
constexpr int N_NODES = 50000;
constexpr int N_EDGES = 800000;
constexpr int EN      = N_EDGES + N_NODES;   // edges + self loops
constexpr int HEADS   = 4;
constexpr int OUT_CH  = 32;
constexpr int HC      = HEADS * OUT_CH;      // 128
constexpr float NEG_SLOPE = 0.2f;
constexpr float EPS_LN    = 1e-5f;

constexpr int SCAN_BLK = 1024;
constexpr int SCAN_NB  = (N_NODES + SCAN_BLK - 1) / SCAN_BLK;  // 49

// ---------- Kernel 1: h = x @ W (+ att dots), W in registers, no LDS ----------
// 256 threads: c = t>>1 (output channel), kg = t&1 (k half). Thread holds
// W[kg*64 .. kg*64+63][c] in 64 VGPRs. Wave w covers channels 32w..32w+31
// (= head w), so att-dot reduction is in-wave (even-lane parity group).
__global__ __launch_bounds__(256, 4)
void gemm_att(const float* __restrict__ x, const float* __restrict__ W,
              const float* __restrict__ att_s, const float* __restrict__ att_d,
              float* __restrict__ h, float* __restrict__ asrc, float* __restrict__ adst)
{
    const int t    = threadIdx.x;
    const int c    = t >> 1;        // 0..127
    const int kg   = t & 1;         // k half
    const int lane = t & 63;
    const int wv   = t >> 6;        // wave index == head

    float Wr[64];
    #pragma unroll
    for (int j = 0; j < 64; ++j)
        Wr[j] = W[(kg * 64 + j) * HC + c];

    const float as = att_s[c];      // flat [H][C] index == c
    const float ad = att_d[c];

    for (int row0 = blockIdx.x * 4; row0 < N_NODES; row0 += gridDim.x * 4) {
        float acc[4] = {0.f, 0.f, 0.f, 0.f};
        #pragma unroll
        for (int r = 0; r < 4; ++r) {
            const float4* xr = (const float4*)(x + (size_t)(row0 + r) * HC + kg * 64);
            #pragma unroll
            for (int j = 0; j < 16; ++j) {
                const float4 xv = xr[j];     // broadcast within 32-lane groups
                acc[r] += Wr[4*j+0] * xv.x + Wr[4*j+1] * xv.y
                        + Wr[4*j+2] * xv.z + Wr[4*j+3] * xv.w;
            }
        }
        #pragma unroll
        for (int r = 0; r < 4; ++r) {
            const float accf = acc[r] + __shfl_xor(acc[r], 1, 64);  // join k halves
            if (kg == 0) h[(size_t)(row0 + r) * HC + c] = accf;
            float vs = accf * as;
            float vd = accf * ad;
            #pragma unroll
            for (int mb = 2; mb <= 32; mb <<= 1) {   // sum over same-parity lanes
                vs += __shfl_xor(vs, mb, 64);
                vd += __shfl_xor(vd, mb, 64);
            }
            if (lane == 0) {
                asrc[(row0 + r) * HEADS + wv] = vs;
                adst[(row0 + r) * HEADS + wv] = vd;
            }
        }
    }
}

// ---------- Kernel 2: histogram of in-degrees (incl. self loops) ----------
__global__ __launch_bounds__(256)
void deg_hist(const int* __restrict__ ei, unsigned* __restrict__ deg) {
    const int e = blockIdx.x * 256 + threadIdx.x;
    if (e >= EN) return;
    const int dst = (e < N_EDGES) ? ei[N_EDGES + e] : (e - N_EDGES);
    atomicAdd(&deg[dst], 1u);
}

// ---------- Kernel 3a: per-block exclusive scan + block totals ----------
__global__ __launch_bounds__(SCAN_BLK)
void scan_part(const unsigned* __restrict__ deg, unsigned* __restrict__ rs,
               unsigned* __restrict__ bsum)
{
    __shared__ unsigned wsum[16];
    const int tid = threadIdx.x, lane = tid & 63, w = tid >> 6;
    const int i = blockIdx.x * SCAN_BLK + tid;
    const unsigned v = (i < N_NODES) ? deg[i] : 0u;
    unsigned incl = v;
    #pragma unroll
    for (int off = 1; off < 64; off <<= 1) {
        const unsigned nb = __shfl_up(incl, off, 64);
        if (lane >= off) incl += nb;
    }
    if (lane == 63) wsum[w] = incl;
    __syncthreads();
    unsigned woff = 0, total = 0;
    #pragma unroll
    for (int j = 0; j < 16; ++j) {
        const unsigned tv = wsum[j];
        if (j < w) woff += tv;
        total += tv;
    }
    if (i < N_NODES) rs[i] = woff + incl - v;    // block-local exclusive
    if (tid == 0) bsum[blockIdx.x] = total;
}

// ---------- Kernel 3b: exclusive scan of the 49 block totals (one wave) ----------
__global__ __launch_bounds__(64)
void scan_tops(unsigned* __restrict__ bsum)
{
    const int lane = threadIdx.x;
    const unsigned v = (lane < SCAN_NB) ? bsum[lane] : 0u;
    unsigned incl = v;
    #pragma unroll
    for (int off = 1; off < 64; off <<= 1) {
        const unsigned nb = __shfl_up(incl, off, 64);
        if (lane >= off) incl += nb;
    }
    if (lane < SCAN_NB) bsum[lane] = incl - v;   // exclusive
}

// ---------- Kernel 3c: add block offsets ----------
__global__ __launch_bounds__(SCAN_BLK)
void scan_add(const unsigned* __restrict__ bsum, unsigned* __restrict__ rs)
{
    const int i = blockIdx.x * SCAN_BLK + threadIdx.x;
    if (i < N_NODES) rs[i] += bsum[blockIdx.x];
    if (i == 0) rs[N_NODES] = (unsigned)EN;
}

// ---------- Kernel 4: scatter edges into CSR order (store src only) ----------
__global__ __launch_bounds__(256)
void scatter_edges(const int* __restrict__ ei, const unsigned* __restrict__ rs,
                   unsigned* __restrict__ cursor, int* __restrict__ esrc) {
    const int e = blockIdx.x * 256 + threadIdx.x;
    if (e >= EN) return;
    const int src = (e < N_EDGES) ? ei[e] : (e - N_EDGES);
    const int dst = (e < N_EDGES) ? ei[N_EDGES + e] : (e - N_EDGES);
    const unsigned pos = rs[dst] + atomicAdd(&cursor[dst], 1u);
    esrc[pos] = src;
}

// ---------- Kernel 5: fused aggregate + epilogue, ONE WAVE per node ----------
// lane owns channels {2*lane, 2*lane+1} (same head = lane>>4): one online-softmax
// state per lane, float2 h gathers (512B/edge per wave), in-wave LN reduce.
__global__ __launch_bounds__(256, 4)
void gat_aggregate(const int* __restrict__ esrc, const unsigned* __restrict__ rs,
                   const float* __restrict__ asrc, const float* __restrict__ adst,
                   const float* __restrict__ h, const float* __restrict__ x,
                   const float* __restrict__ bias, const float* __restrict__ gamma,
                   const float* __restrict__ beta, float* __restrict__ out)
{
    const int wv   = threadIdx.x >> 6;
    const int lane = threadIdx.x & 63;
    const int n    = blockIdx.x * 4 + wv;        // grid covers exactly N_NODES
    const int hh   = lane >> 4;                  // head of channels 2l, 2l+1
    const int start = (int)rs[n], end = (int)rs[n + 1];
    const float adn = adst[n * HEADS + hh];

    float m = -INFINITY, s = 0.f, ax = 0.f, ay = 0.f;
    int pos = start;
    for (; pos + 1 < end; pos += 2) {
        const int s0 = esrc[pos], s1 = esrc[pos + 1];
        float v0 = asrc[s0 * HEADS + hh] + adn;
        float v1 = asrc[s1 * HEADS + hh] + adn;
        v0 = (v0 > 0.f) ? v0 : NEG_SLOPE * v0;
        v1 = (v1 > 0.f) ? v1 : NEG_SLOPE * v1;
        const float2 h0 = ((const float2*)(h + (size_t)s0 * HC))[lane];
        const float2 h1 = ((const float2*)(h + (size_t)s1 * HC))[lane];
        const float nm = fmaxf(m, fmaxf(v0, v1));
        const float cs = expf(m - nm);           // 0 when m == -inf
        const float w0 = expf(v0 - nm);
        const float w1 = expf(v1 - nm);
        ax = ax * cs + w0 * h0.x + w1 * h1.x;
        ay = ay * cs + w0 * h0.y + w1 * h1.y;
        s  = s  * cs + w0 + w1;
        m = nm;
    }
    if (pos < end) {
        const int s0 = esrc[pos];
        float v0 = asrc[s0 * HEADS + hh] + adn;
        v0 = (v0 > 0.f) ? v0 : NEG_SLOPE * v0;
        const float2 h0 = ((const float2*)(h + (size_t)s0 * HC))[lane];
        const float nm = fmaxf(m, v0);
        const float cs = expf(m - nm);
        const float w0 = expf(v0 - nm);
        ax = ax * cs + w0 * h0.x;
        ay = ay * cs + w0 * h0.y;
        s  = s  * cs + w0;
    }

    const float inv = 1.f / (s + 1e-16f);
    const float2 bv = ((const float2*)bias)[lane];
    const float2 xv = ((const float2*)(x + (size_t)n * HC))[lane];
    float ox = ax * inv + bv.x;
    float oy = ay * inv + bv.y;
    ox = (ox > 0.f) ? ox : expm1f(ox);
    oy = (oy > 0.f) ? oy : expm1f(oy);
    ox += xv.x; oy += xv.y;

    float ss = ox + oy, sq = ox * ox + oy * oy;
    #pragma unroll
    for (int off = 32; off >= 1; off >>= 1) {
        ss += __shfl_xor(ss, off, 64);
        sq += __shfl_xor(sq, off, 64);
    }
    const float mu   = ss * (1.f / HC);
    const float var  = sq * (1.f / HC) - mu * mu;
    const float rstd = rsqrtf(var + EPS_LN);
    const float2 gv = ((const float2*)gamma)[lane];
    const float2 bt = ((const float2*)beta)[lane];
    float2 ov;
    ov.x = (ox - mu) * rstd * gv.x + bt.x;
    ov.y = (oy - mu) * rstd * gv.y + bt.y;
    ((float2*)(out + (size_t)n * HC))[lane] = ov;
}

extern "C" void kernel_launch(void* const* d_in, const int* in_sizes, int n_in,
                              void* d_out, int out_size, void* d_ws, size_t ws_size,
                              hipStream_t stream) {
    const float* x     = (const float*)d_in[0];
    const int*   ei    = (const int*)  d_in[1];
    const float* W     = (const float*)d_in[2];
    const float* att_s = (const float*)d_in[3];
    const float* att_d = (const float*)d_in[4];
    const float* bias  = (const float*)d_in[5];
    const float* gamma = (const float*)d_in[6];
    const float* beta  = (const float*)d_in[7];
    float* out = (float*)d_out;

    // workspace layout (bytes)
    char* ws = (char*)d_ws;
    float*    h      = (float*)   (ws);              // 25,600,000
    float*    asrc   = (float*)   (ws + 25600000);   //    800,000
    float*    adst   = (float*)   (ws + 26400000);   //    800,000
    unsigned* deg    = (unsigned*)(ws + 27200000);   //    200,000
    unsigned* cursor = (unsigned*)(ws + 27400000);   //    200,000
    unsigned* rs     = (unsigned*)(ws + 27600000);   //    200,004 (N+1)
    unsigned* bsum   = (unsigned*)(ws + 27800192);   //        196
    int*      esrc   = (int*)     (ws + 27800448);   //  3,400,000  (total ~31.2 MB)

    hipMemsetAsync(deg,    0, (size_t)N_NODES * 4, stream);
    hipMemsetAsync(cursor, 0, (size_t)N_NODES * 4, stream);

    gemm_att<<<1024, 256, 0, stream>>>(x, W, att_s, att_d, h, asrc, adst);

    const int e_grid = (EN + 255) / 256;
    deg_hist     <<<e_grid, 256, 0, stream>>>(ei, deg);
    scan_part    <<<SCAN_NB, SCAN_BLK, 0, stream>>>(deg, rs, bsum);
    scan_tops    <<<1, 64, 0, stream>>>(bsum);
    scan_add     <<<SCAN_NB, SCAN_BLK, 0, stream>>>(bsum, rs);
    scatter_edges<<<e_grid, 256, 0, stream>>>(ei, rs, cursor, esrc);

    gat_aggregate<<<N_NODES / 4, 256, 0, stream>>>(esrc, rs, asrc, adst, h, x,
                                                   bias, gamma, beta, out);
}

// Round 6
// 940.666 us; speedup vs baseline: 1.0398x; 1.0398x over previous
//
#include <hip/hip_runtime.h>
#include <hip/hip_bf16.h>

// Problem constants (from reference)
constexpr int N_NODES = 50000;
constexpr int N_EDGES = 800000;
constexpr int EN      = N_EDGES + N_NODES;   // edges + self loops
constexpr int HEADS   = 4;
constexpr int OUT_CH  = 32;
constexpr int HC      = HEADS * OUT_CH;      // 128
constexpr float NEG_SLOPE = 0.2f;
constexpr float EPS_LN    = 1e-5f;

constexpr int SCAN_BLK = 1024;
constexpr int SCAN_NB  = (N_NODES + SCAN_BLK - 1) / SCAN_BLK;  // 49

// ---------- Kernel 1: h = x @ W (+ att dots) ----------
// 512 threads: c = t&127 (output channel), rg = t>>7 (row group, 4 rows each).
// Whole W in LDS (64 KB) + 16-row x tile (8 KB) = 72 KB -> 2 blocks/CU
// = 16 waves/CU (~50% occ), vs round-3's 4 waves/CU at the same LDS layout.
__global__ __launch_bounds__(512, 2)
void gemm_att(const float* __restrict__ x, const float* __restrict__ W,
              const float* __restrict__ att_s, const float* __restrict__ att_d,
              float* __restrict__ h, float* __restrict__ asrc, float* __restrict__ adst)
{
    __shared__ float Wl[HC * HC];       // 64 KB
    __shared__ float xs[16][HC];        // 8 KB
    const int t  = threadIdx.x;         // 0..511
    const int c  = t & 127;             // output channel
    const int rg = t >> 7;              // row group 0..3

    {   // stage W once (float4, coalesced)
        const float4* Wsrc = (const float4*)W;
        float4* Wd = (float4*)Wl;
        #pragma unroll
        for (int i = 0; i < 8; ++i) Wd[t + i * 512] = Wsrc[t + i * 512];
    }
    const float as = att_s[c];
    const float ad = att_d[c];

    for (int row0 = blockIdx.x * 16; row0 < N_NODES; row0 += gridDim.x * 16) {
        __syncthreads();                 // xs readers of prev batch done (covers W stage too)
        ((float4*)&xs[0][0])[t] = ((const float4*)(x + (size_t)row0 * HC))[t];
        __syncthreads();

        float acc[4] = {0.f, 0.f, 0.f, 0.f};
        for (int k = 0; k < HC; k += 4) {
            const float w0 = Wl[(k + 0) * HC + c];   // stride-1 over c: 2-way, free
            const float w1 = Wl[(k + 1) * HC + c];
            const float w2 = Wl[(k + 2) * HC + c];
            const float w3 = Wl[(k + 3) * HC + c];
            #pragma unroll
            for (int r = 0; r < 4; ++r) {
                const float4 xv = *(const float4*)&xs[rg * 4 + r][k];  // wave-broadcast
                acc[r] += w0 * xv.x + w1 * xv.y + w2 * xv.z + w3 * xv.w;
            }
        }

        #pragma unroll
        for (int r = 0; r < 4; ++r) {
            const int row = row0 + rg * 4 + r;
            h[(size_t)row * HC + c] = acc[r];
            float vs = acc[r] * as;
            float vd = acc[r] * ad;
            #pragma unroll
            for (int mb = 16; mb >= 1; mb >>= 1) {   // reduce 32-lane head group
                vs += __shfl_xor(vs, mb, 64);
                vd += __shfl_xor(vd, mb, 64);
            }
            if ((t & 31) == 0) {
                asrc[row * HEADS + (c >> 5)] = vs;
                adst[row * HEADS + (c >> 5)] = vd;
            }
        }
    }
}

// ---------- Kernel 2: histogram of in-degrees (incl. self loops) ----------
__global__ __launch_bounds__(256)
void deg_hist(const int* __restrict__ ei, unsigned* __restrict__ deg) {
    const int e = blockIdx.x * 256 + threadIdx.x;
    if (e >= EN) return;
    const int dst = (e < N_EDGES) ? ei[N_EDGES + e] : (e - N_EDGES);
    atomicAdd(&deg[dst], 1u);
}

// ---------- Kernel 3a: per-block exclusive scan + block totals ----------
__global__ __launch_bounds__(SCAN_BLK)
void scan_part(const unsigned* __restrict__ deg, unsigned* __restrict__ rs,
               unsigned* __restrict__ bsum)
{
    __shared__ unsigned wsum[16];
    const int tid = threadIdx.x, lane = tid & 63, w = tid >> 6;
    const int i = blockIdx.x * SCAN_BLK + tid;
    const unsigned v = (i < N_NODES) ? deg[i] : 0u;
    unsigned incl = v;
    #pragma unroll
    for (int off = 1; off < 64; off <<= 1) {
        const unsigned nb = __shfl_up(incl, off, 64);
        if (lane >= off) incl += nb;
    }
    if (lane == 63) wsum[w] = incl;
    __syncthreads();
    unsigned woff = 0, total = 0;
    #pragma unroll
    for (int j = 0; j < 16; ++j) {
        const unsigned tv = wsum[j];
        if (j < w) woff += tv;
        total += tv;
    }
    if (i < N_NODES) rs[i] = woff + incl - v;    // block-local exclusive
    if (tid == 0) bsum[blockIdx.x] = total;
}

// ---------- Kernel 3b: exclusive scan of the 49 block totals (one wave) ----------
__global__ __launch_bounds__(64)
void scan_tops(unsigned* __restrict__ bsum)
{
    const int lane = threadIdx.x;
    const unsigned v = (lane < SCAN_NB) ? bsum[lane] : 0u;
    unsigned incl = v;
    #pragma unroll
    for (int off = 1; off < 64; off <<= 1) {
        const unsigned nb = __shfl_up(incl, off, 64);
        if (lane >= off) incl += nb;
    }
    if (lane < SCAN_NB) bsum[lane] = incl - v;   // exclusive
}

// ---------- Kernel 3c: add block offsets ----------
__global__ __launch_bounds__(SCAN_BLK)
void scan_add(const unsigned* __restrict__ bsum, unsigned* __restrict__ rs)
{
    const int i = blockIdx.x * SCAN_BLK + threadIdx.x;
    if (i < N_NODES) rs[i] += bsum[blockIdx.x];
    if (i == 0) rs[N_NODES] = (unsigned)EN;
}

// ---------- Kernel 4: scatter edges into CSR order (store src only) ----------
__global__ __launch_bounds__(256)
void scatter_edges(const int* __restrict__ ei, const unsigned* __restrict__ rs,
                   unsigned* __restrict__ cursor, int* __restrict__ esrc) {
    const int e = blockIdx.x * 256 + threadIdx.x;
    if (e >= EN) return;
    const int src = (e < N_EDGES) ? ei[e] : (e - N_EDGES);
    const int dst = (e < N_EDGES) ? ei[N_EDGES + e] : (e - N_EDGES);
    const unsigned pos = rs[dst] + atomicAdd(&cursor[dst], 1u);
    esrc[pos] = src;
}

// ---------- Kernel 5: fused aggregate + epilogue, ONE WAVE per node ----------
// lane owns channels {2*lane, 2*lane+1} (same head = lane>>4): one online-softmax
// state per lane, float2 h gathers (512B/edge per wave), in-wave LN reduce.
__global__ __launch_bounds__(256, 4)
void gat_aggregate(const int* __restrict__ esrc, const unsigned* __restrict__ rs,
                   const float* __restrict__ asrc, const float* __restrict__ adst,
                   const float* __restrict__ h, const float* __restrict__ x,
                   const float* __restrict__ bias, const float* __restrict__ gamma,
                   const float* __restrict__ beta, float* __restrict__ out)
{
    const int wv   = threadIdx.x >> 6;
    const int lane = threadIdx.x & 63;
    const int n    = blockIdx.x * 4 + wv;        // grid covers exactly N_NODES
    const int hh   = lane >> 4;                  // head of channels 2l, 2l+1
    const int start = (int)rs[n], end = (int)rs[n + 1];
    const float adn = adst[n * HEADS + hh];

    float m = -INFINITY, s = 0.f, ax = 0.f, ay = 0.f;
    int pos = start;
    for (; pos + 1 < end; pos += 2) {
        const int s0 = esrc[pos], s1 = esrc[pos + 1];
        float v0 = asrc[s0 * HEADS + hh] + adn;
        float v1 = asrc[s1 * HEADS + hh] + adn;
        v0 = (v0 > 0.f) ? v0 : NEG_SLOPE * v0;
        v1 = (v1 > 0.f) ? v1 : NEG_SLOPE * v1;
        const float2 h0 = ((const float2*)(h + (size_t)s0 * HC))[lane];
        const float2 h1 = ((const float2*)(h + (size_t)s1 * HC))[lane];
        const float nm = fmaxf(m, fmaxf(v0, v1));
        const float cs = expf(m - nm);           // 0 when m == -inf
        const float w0 = expf(v0 - nm);
        const float w1 = expf(v1 - nm);
        ax = ax * cs + w0 * h0.x + w1 * h1.x;
        ay = ay * cs + w0 * h0.y + w1 * h1.y;
        s  = s  * cs + w0 + w1;
        m = nm;
    }
    if (pos < end) {
        const int s0 = esrc[pos];
        float v0 = asrc[s0 * HEADS + hh] + adn;
        v0 = (v0 > 0.f) ? v0 : NEG_SLOPE * v0;
        const float2 h0 = ((const float2*)(h + (size_t)s0 * HC))[lane];
        const float nm = fmaxf(m, v0);
        const float cs = expf(m - nm);
        const float w0 = expf(v0 - nm);
        ax = ax * cs + w0 * h0.x;
        ay = ay * cs + w0 * h0.y;
        s  = s  * cs + w0;
    }

    const float inv = 1.f / (s + 1e-16f);
    const float2 bv = ((const float2*)bias)[lane];
    const float2 xv = ((const float2*)(x + (size_t)n * HC))[lane];
    float ox = ax * inv + bv.x;
    float oy = ay * inv + bv.y;
    ox = (ox > 0.f) ? ox : expm1f(ox);
    oy = (oy > 0.f) ? oy : expm1f(oy);
    ox += xv.x; oy += xv.y;

    float ss = ox + oy, sq = ox * ox + oy * oy;
    #pragma unroll
    for (int off = 32; off >= 1; off >>= 1) {
        ss += __shfl_xor(ss, off, 64);
        sq += __shfl_xor(sq, off, 64);
    }
    const float mu   = ss * (1.f / HC);
    const float var  = sq * (1.f / HC) - mu * mu;
    const float rstd = rsqrtf(var + EPS_LN);
    const float2 gv = ((const float2*)gamma)[lane];
    const float2 bt = ((const float2*)beta)[lane];
    float2 ov;
    ov.x = (ox - mu) * rstd * gv.x + bt.x;
    ov.y = (oy - mu) * rstd * gv.y + bt.y;
    ((float2*)(out + (size_t)n * HC))[lane] = ov;
}

extern "C" void kernel_launch(void* const* d_in, const int* in_sizes, int n_in,
                              void* d_out, int out_size, void* d_ws, size_t ws_size,
                              hipStream_t stream) {
    const float* x     = (const float*)d_in[0];
    const int*   ei    = (const int*)  d_in[1];
    const float* W     = (const float*)d_in[2];
    const float* att_s = (const float*)d_in[3];
    const float* att_d = (const float*)d_in[4];
    const float* bias  = (const float*)d_in[5];
    const float* gamma = (const float*)d_in[6];
    const float* beta  = (const float*)d_in[7];
    float* out = (float*)d_out;

    // workspace layout (bytes)
    char* ws = (char*)d_ws;
    float*    h      = (float*)   (ws);              // 25,600,000
    float*    asrc   = (float*)   (ws + 25600000);   //    800,000
    float*    adst   = (float*)   (ws + 26400000);   //    800,000
    unsigned* deg    = (unsigned*)(ws + 27200000);   //    200,000
    unsigned* cursor = (unsigned*)(ws + 27400000);   //    200,000
    unsigned* rs     = (unsigned*)(ws + 27600000);   //    200,004 (N+1)
    unsigned* bsum   = (unsigned*)(ws + 27800192);   //        196
    int*      esrc   = (int*)     (ws + 27800448);   //  3,400,000  (total ~31.2 MB)

    hipMemsetAsync(deg,    0, (size_t)N_NODES * 4, stream);
    hipMemsetAsync(cursor, 0, (size_t)N_NODES * 4, stream);

    gemm_att<<<512, 512, 0, stream>>>(x, W, att_s, att_d, h, asrc, adst);

    const int e_grid = (EN + 255) / 256;
    deg_hist     <<<e_grid, 256, 0, stream>>>(ei, deg);
    scan_part    <<<SCAN_NB, SCAN_BLK, 0, stream>>>(deg, rs, bsum);
    scan_tops    <<<1, 64, 0, stream>>>(bsum);
    scan_add     <<<SCAN_NB, SCAN_BLK, 0, stream>>>(bsum, rs);
    scatter_edges<<<e_grid, 256, 0, stream>>>(ei, rs, cursor, esrc);

    gat_aggregate<<<N_NODES / 4, 256, 0, stream>>>(esrc, rs, asrc, adst, h, x,
                                                   bias, gamma, beta, out);
}

// Round 8
// 396.673 us; speedup vs baseline: 2.4659x; 2.3714x over previous
//
#include <hip/hip_runtime.h>
#include <hip/hip_bf16.h>

// Problem constants (from reference)
constexpr int N_NODES = 50000;
constexpr int N_EDGES = 800000;
constexpr int EN      = N_EDGES + N_NODES;   // edges + self loops
constexpr int HEADS   = 4;
constexpr int OUT_CH  = 32;
constexpr int HC      = HEADS * OUT_CH;      // 128
constexpr float NEG_SLOPE = 0.2f;
constexpr float EPS_LN    = 1e-5f;

constexpr int SCAN_BLK = 1024;
constexpr int SCAN_NB  = (N_NODES + SCAN_BLK - 1) / SCAN_BLK;  // 49

// ---------- Kernel 1: h = x @ W (+ att dots) ----------
// Round-3-proven structure (110us, clean 40MB traffic), widened to 256 threads:
// c = t&127 (output channel), rg = t>>7 (row group, 4 rows each, 8-row tile).
// LDS 68KB -> 2 blocks/CU = 8 waves/CU (2/SIMD), double round-3's occupancy.
// NOTE: no min-waves arg in __launch_bounds__ — r4/r6 showed it caps VGPRs
// (64/128 resp.) and silently spills the k-loop to scratch (2.7-2.9 GB HBM).
__global__ __launch_bounds__(256)
void gemm_att(const float* __restrict__ x, const float* __restrict__ W,
              const float* __restrict__ att_s, const float* __restrict__ att_d,
              float* __restrict__ h, float* __restrict__ asrc, float* __restrict__ adst)
{
    __shared__ float Wl[HC * HC];       // 64 KB
    __shared__ float xs[8][HC];         // 4 KB
    const int t  = threadIdx.x;         // 0..255
    const int c  = t & 127;             // output channel
    const int rg = t >> 7;              // row group 0..1

    {   // stage W once (float4, coalesced): 4096 float4 / 256 thr = 16 each
        const float4* Ws = (const float4*)W;
        float4* Wd = (float4*)Wl;
        #pragma unroll
        for (int i = 0; i < 16; ++i) Wd[t + i * 256] = Ws[t + i * 256];
    }
    const float as = att_s[c];
    const float ad = att_d[c];

    for (int row0 = blockIdx.x * 8; row0 < N_NODES; row0 += gridDim.x * 8) {
        __syncthreads();                 // xs readers of prev batch done (covers W stage too)
        // 8 rows x 128 ch = 256 float4, one per thread
        ((float4*)&xs[0][0])[t] = ((const float4*)(x + (size_t)row0 * HC))[t];
        __syncthreads();

        float acc[4] = {0.f, 0.f, 0.f, 0.f};
        for (int k = 0; k < HC; k += 4) {
            const float w0 = Wl[(k + 0) * HC + c];   // stride-1 over c: 2-way, free
            const float w1 = Wl[(k + 1) * HC + c];
            const float w2 = Wl[(k + 2) * HC + c];
            const float w3 = Wl[(k + 3) * HC + c];
            #pragma unroll
            for (int r = 0; r < 4; ++r) {
                const float4 xv = *(const float4*)&xs[rg * 4 + r][k];  // wave-broadcast
                acc[r] += w0 * xv.x + w1 * xv.y + w2 * xv.z + w3 * xv.w;
            }
        }

        #pragma unroll
        for (int r = 0; r < 4; ++r) {
            const int row = row0 + rg * 4 + r;
            h[(size_t)row * HC + c] = acc[r];
            float vs = acc[r] * as;
            float vd = acc[r] * ad;
            #pragma unroll
            for (int mb = 16; mb >= 1; mb >>= 1) {   // reduce 32-lane head group
                vs += __shfl_xor(vs, mb, 64);
                vd += __shfl_xor(vd, mb, 64);
            }
            if ((t & 31) == 0) {
                asrc[row * HEADS + (c >> 5)] = vs;
                adst[row * HEADS + (c >> 5)] = vd;
            }
        }
    }
}

// ---------- Kernel 2: histogram of in-degrees (incl. self loops) ----------
__global__ __launch_bounds__(256)
void deg_hist(const int* __restrict__ ei, unsigned* __restrict__ deg) {
    const int e = blockIdx.x * 256 + threadIdx.x;
    if (e >= EN) return;
    const int dst = (e < N_EDGES) ? ei[N_EDGES + e] : (e - N_EDGES);
    atomicAdd(&deg[dst], 1u);
}

// ---------- Kernel 3a: per-block exclusive scan + block totals ----------
__global__ __launch_bounds__(SCAN_BLK)
void scan_part(const unsigned* __restrict__ deg, unsigned* __restrict__ rs,
               unsigned* __restrict__ bsum)
{
    __shared__ unsigned wsum[16];
    const int tid = threadIdx.x, lane = tid & 63, w = tid >> 6;
    const int i = blockIdx.x * SCAN_BLK + tid;
    const unsigned v = (i < N_NODES) ? deg[i] : 0u;
    unsigned incl = v;
    #pragma unroll
    for (int off = 1; off < 64; off <<= 1) {
        const unsigned nb = __shfl_up(incl, off, 64);
        if (lane >= off) incl += nb;
    }
    if (lane == 63) wsum[w] = incl;
    __syncthreads();
    unsigned woff = 0, total = 0;
    #pragma unroll
    for (int j = 0; j < 16; ++j) {
        const unsigned tv = wsum[j];
        if (j < w) woff += tv;
        total += tv;
    }
    if (i < N_NODES) rs[i] = woff + incl - v;    // block-local exclusive
    if (tid == 0) bsum[blockIdx.x] = total;
}

// ---------- Kernel 3b: exclusive scan of the 49 block totals (one wave) ----------
__global__ __launch_bounds__(64)
void scan_tops(unsigned* __restrict__ bsum)
{
    const int lane = threadIdx.x;
    const unsigned v = (lane < SCAN_NB) ? bsum[lane] : 0u;
    unsigned incl = v;
    #pragma unroll
    for (int off = 1; off < 64; off <<= 1) {
        const unsigned nb = __shfl_up(incl, off, 64);
        if (lane >= off) incl += nb;
    }
    if (lane < SCAN_NB) bsum[lane] = incl - v;   // exclusive
}

// ---------- Kernel 3c: add block offsets ----------
__global__ __launch_bounds__(SCAN_BLK)
void scan_add(const unsigned* __restrict__ bsum, unsigned* __restrict__ rs)
{
    const int i = blockIdx.x * SCAN_BLK + threadIdx.x;
    if (i < N_NODES) rs[i] += bsum[blockIdx.x];
    if (i == 0) rs[N_NODES] = (unsigned)EN;
}

// ---------- Kernel 4: scatter edges into CSR order (store src only) ----------
__global__ __launch_bounds__(256)
void scatter_edges(const int* __restrict__ ei, const unsigned* __restrict__ rs,
                   unsigned* __restrict__ cursor, int* __restrict__ esrc) {
    const int e = blockIdx.x * 256 + threadIdx.x;
    if (e >= EN) return;
    const int src = (e < N_EDGES) ? ei[e] : (e - N_EDGES);
    const int dst = (e < N_EDGES) ? ei[N_EDGES + e] : (e - N_EDGES);
    const unsigned pos = rs[dst] + atomicAdd(&cursor[dst], 1u);
    esrc[pos] = src;
}

// ---------- Kernel 5: fused aggregate + epilogue, ONE WAVE per node ----------
// lane owns channels {2*lane, 2*lane+1} (same head = lane>>4): one online-softmax
// state per lane, float2 h gathers (512B/edge per wave), in-wave LN reduce.
__global__ __launch_bounds__(256, 4)
void gat_aggregate(const int* __restrict__ esrc, const unsigned* __restrict__ rs,
                   const float* __restrict__ asrc, const float* __restrict__ adst,
                   const float* __restrict__ h, const float* __restrict__ x,
                   const float* __restrict__ bias, const float* __restrict__ gamma,
                   const float* __restrict__ beta, float* __restrict__ out)
{
    const int wv   = threadIdx.x >> 6;
    const int lane = threadIdx.x & 63;
    const int n    = blockIdx.x * 4 + wv;        // grid covers exactly N_NODES
    const int hh   = lane >> 4;                  // head of channels 2l, 2l+1
    const int start = (int)rs[n], end = (int)rs[n + 1];
    const float adn = adst[n * HEADS + hh];

    float m = -INFINITY, s = 0.f, ax = 0.f, ay = 0.f;
    int pos = start;
    for (; pos + 1 < end; pos += 2) {
        const int s0 = esrc[pos], s1 = esrc[pos + 1];
        float v0 = asrc[s0 * HEADS + hh] + adn;
        float v1 = asrc[s1 * HEADS + hh] + adn;
        v0 = (v0 > 0.f) ? v0 : NEG_SLOPE * v0;
        v1 = (v1 > 0.f) ? v1 : NEG_SLOPE * v1;
        const float2 h0 = ((const float2*)(h + (size_t)s0 * HC))[lane];
        const float2 h1 = ((const float2*)(h + (size_t)s1 * HC))[lane];
        const float nm = fmaxf(m, fmaxf(v0, v1));
        const float cs = expf(m - nm);           // 0 when m == -inf
        const float w0 = expf(v0 - nm);
        const float w1 = expf(v1 - nm);
        ax = ax * cs + w0 * h0.x + w1 * h1.x;
        ay = ay * cs + w0 * h0.y + w1 * h1.y;
        s  = s  * cs + w0 + w1;
        m = nm;
    }
    if (pos < end) {
        const int s0 = esrc[pos];
        float v0 = asrc[s0 * HEADS + hh] + adn;
        v0 = (v0 > 0.f) ? v0 : NEG_SLOPE * v0;
        const float2 h0 = ((const float2*)(h + (size_t)s0 * HC))[lane];
        const float nm = fmaxf(m, v0);
        const float cs = expf(m - nm);
        const float w0 = expf(v0 - nm);
        ax = ax * cs + w0 * h0.x;
        ay = ay * cs + w0 * h0.y;
        s  = s  * cs + w0;
    }

    const float inv = 1.f / (s + 1e-16f);
    const float2 bv = ((const float2*)bias)[lane];
    const float2 xv = ((const float2*)(x + (size_t)n * HC))[lane];
    float ox = ax * inv + bv.x;
    float oy = ay * inv + bv.y;
    ox = (ox > 0.f) ? ox : expm1f(ox);
    oy = (oy > 0.f) ? oy : expm1f(oy);
    ox += xv.x; oy += xv.y;

    float ss = ox + oy, sq = ox * ox + oy * oy;
    #pragma unroll
    for (int off = 32; off >= 1; off >>= 1) {
        ss += __shfl_xor(ss, off, 64);
        sq += __shfl_xor(sq, off, 64);
    }
    const float mu   = ss * (1.f / HC);
    const float var  = sq * (1.f / HC) - mu * mu;
    const float rstd = rsqrtf(var + EPS_LN);
    const float2 gv = ((const float2*)gamma)[lane];
    const float2 bt = ((const float2*)beta)[lane];
    float2 ov;
    ov.x = (ox - mu) * rstd * gv.x + bt.x;
    ov.y = (oy - mu) * rstd * gv.y + bt.y;
    ((float2*)(out + (size_t)n * HC))[lane] = ov;
}

extern "C" void kernel_launch(void* const* d_in, const int* in_sizes, int n_in,
                              void* d_out, int out_size, void* d_ws, size_t ws_size,
                              hipStream_t stream) {
    const float* x     = (const float*)d_in[0];
    const int*   ei    = (const int*)  d_in[1];
    const float* W     = (const float*)d_in[2];
    const float* att_s = (const float*)d_in[3];
    const float* att_d = (const float*)d_in[4];
    const float* bias  = (const float*)d_in[5];
    const float* gamma = (const float*)d_in[6];
    const float* beta  = (const float*)d_in[7];
    float* out = (float*)d_out;

    // workspace layout (bytes)
    char* ws = (char*)d_ws;
    float*    h      = (float*)   (ws);              // 25,600,000
    float*    asrc   = (float*)   (ws + 25600000);   //    800,000
    float*    adst   = (float*)   (ws + 26400000);   //    800,000
    unsigned* deg    = (unsigned*)(ws + 27200000);   //    200,000
    unsigned* cursor = (unsigned*)(ws + 27400000);   //    200,000
    unsigned* rs     = (unsigned*)(ws + 27600000);   //    200,004 (N+1)
    unsigned* bsum   = (unsigned*)(ws + 27800192);   //        196
    int*      esrc   = (int*)     (ws + 27800448);   //  3,400,000  (total ~31.2 MB)

    hipMemsetAsync(deg,    0, (size_t)N_NODES * 4, stream);
    hipMemsetAsync(cursor, 0, (size_t)N_NODES * 4, stream);

    gemm_att<<<1024, 256, 0, stream>>>(x, W, att_s, att_d, h, asrc, adst);

    const int e_grid = (EN + 255) / 256;
    deg_hist     <<<e_grid, 256, 0, stream>>>(ei, deg);
    scan_part    <<<SCAN_NB, SCAN_BLK, 0, stream>>>(deg, rs, bsum);
    scan_tops    <<<1, 64, 0, stream>>>(bsum);
    scan_add     <<<SCAN_NB, SCAN_BLK, 0, stream>>>(bsum, rs);
    scatter_edges<<<e_grid, 256, 0, stream>>>(ei, rs, cursor, esrc);

    gat_aggregate<<<N_NODES / 4, 256, 0, stream>>>(esrc, rs, asrc, adst, h, x,
                                                   bias, gamma, beta, out);
}